// Round 1
// baseline (719.376 us; speedup 1.0000x reference)
//
#include <hip/hip_runtime.h>
#include <hip/hip_bf16.h>
#include <stdint.h>

#define NB   16
#define CIN  512
#define COUT 512
#define STY  512
#define HH   64
#define WW   64
#define KT   9          // 3x3 taps
#define KDIM (CIN*KT)   // 4608
#define HP   66         // padded spatial
#define PIX  (HH*WW)    // 4096
#define EPSV 1e-8f

typedef __attribute__((ext_vector_type(8))) __bf16 bf16x8;
typedef __attribute__((ext_vector_type(4))) float floatx4;
typedef unsigned short ushort;

__device__ __forceinline__ ushort f32_to_bf16(float f) {
    union { float f; uint32_t u; } v; v.f = f;
    uint32_t u = v.u;
    u += 0x7fffu + ((u >> 16) & 1u);   // RNE
    return (ushort)(u >> 16);
}

__device__ __forceinline__ void async16(const void* g, void* l) {
    __builtin_amdgcn_global_load_lds(
        (const __attribute__((address_space(1))) uint32_t*)g,
        (__attribute__((address_space(3))) uint32_t*)l, 16, 0, 0);
}

// ---------------- kernel 1: style linear: s[n][ci] ----------------
__global__ void __launch_bounds__(256) style_kernel(
    const float* __restrict__ style, const float* __restrict__ style_w,
    const float* __restrict__ style_b, float* __restrict__ s) {
    int g = blockIdx.x * 256 + threadIdx.x;   // 16*512
    int n = g >> 9, ci = g & 511;
    const float4* wv = (const float4*)(style_w + (size_t)ci * STY);
    const float4* sv = (const float4*)(style + (size_t)n * STY);
    float acc = 0.f;
    for (int j = 0; j < STY / 4; ++j) {
        float4 a = wv[j], b = sv[j];
        acc += a.x * b.x + a.y * b.y + a.z * b.z + a.w * b.w;
    }
    s[g] = acc + style_b[ci];
}

// ------- kernel 2: modulate + demod + transpose to Wt[n][co][kk][ci] bf16 -------
__global__ void __launch_bounds__(256) modw_kernel(
    const float* __restrict__ weight, const float* __restrict__ s,
    ushort* __restrict__ Wt) {
    const int co = blockIdx.x, n = blockIdx.y, t = threadIdx.x;
    const float* wrow = weight + (size_t)co * KDIM;   // [ci][kh][kw]
    const float* srow = s + (size_t)n * CIN;
    float sum = 0.f;
    for (int e = t; e < KDIM; e += 256) {
        int ci = e / 9;
        float m = wrow[e] * srow[ci];
        sum += m * m;
    }
    for (int off = 32; off > 0; off >>= 1) sum += __shfl_down(sum, off, 64);
    __shared__ float red[4];
    int wv = t >> 6, ln = t & 63;
    if (ln == 0) red[wv] = sum;
    __syncthreads();
    float demod = rsqrtf(red[0] + red[1] + red[2] + red[3] + EPSV);
    ushort* orow = Wt + (size_t)(n * COUT + co) * KDIM;
    for (int o = t; o < KDIM; o += 256) {    // o = kk*512 + ci
        int kk = o >> 9, ci = o & 511;
        float m = wrow[ci * 9 + kk] * srow[ci] * demod;
        orow[o] = f32_to_bf16(m);
    }
}

// ------- kernel 3a: zero the padding borders of xt[n][66][66][512] (bf16) -------
__global__ void __launch_bounds__(256) zborder_kernel(unsigned long long* __restrict__ xt8) {
    int idx = blockIdx.x * 256 + threadIdx.x;  // 16*260*128 exactly
    int k = idx & 127;
    int rem = idx >> 7;
    int slot = rem % 260;
    int n = rem / 260;
    int hp, wp;
    if (slot < 66)       { hp = 0;  wp = slot; }
    else if (slot < 132) { hp = 65; wp = slot - 66; }
    else { int r = slot - 132; hp = 1 + (r >> 1); wp = (r & 1) ? 65 : 0; }
    xt8[(size_t)((n * HP + hp) * HP + wp) * 128 + k] = 0ull;
}

// ------- kernel 3b: NCHW fp32 -> padded NHWC bf16 transpose -------
__global__ void __launch_bounds__(256) xpose_kernel(
    const float* __restrict__ x, ushort* __restrict__ xt) {
    const int h = blockIdx.x;   // 0..63
    const int n = blockIdx.y;
    const int t = threadIdx.x;
    __shared__ float tile[32][65];
    for (int ci0 = 0; ci0 < CIN; ci0 += 32) {
        #pragma unroll
        for (int r = 0; r < 8; ++r) {
            int cil = r * 4 + (t >> 6);
            int w = t & 63;
            tile[cil][w] = x[(((size_t)n * CIN + ci0 + cil) * HH + h) * WW + w];
        }
        __syncthreads();
        #pragma unroll
        for (int r = 0; r < 8; ++r) {
            int w = r * 8 + (t >> 5);
            int cil = t & 31;
            xt[(((size_t)n * HP + h + 1) * HP + (w + 1)) * CIN + ci0 + cil] =
                f32_to_bf16(tile[cil][w]);
        }
        __syncthreads();
    }
}

// ------- kernel 4: implicit-GEMM conv, m97 structure (128x128 tile, BK=32) -------
__global__ void __launch_bounds__(256) conv_kernel(
    const ushort* __restrict__ Wt, const ushort* __restrict__ xt,
    const float* __restrict__ noise, const float* __restrict__ nw_p,
    float* __restrict__ out) {
    __shared__ short lds[8192];          // A: [0,4096) B: [4096,8192)  (bf16 elems)
    const int t = threadIdx.x;
    const int pos0 = blockIdx.x * 128;   // 32 pixel tiles (2 image rows each)
    const int h0 = blockIdx.x * 2;
    const int co0 = blockIdx.y * 128;    // 4 cout tiles
    const int n = blockIdx.z;            // 16 samples

    // staging bases: per call q, element e = q*2048 + t*8 of the 32x128 tile
    const int e0 = t * 8;
    size_t gA[2], gB[2];
    #pragma unroll
    for (int q = 0; q < 2; ++q) {
        int e = q * 2048 + e0;
        int row = e >> 5, c = e & 31;
        gA[q] = (size_t)(n * COUT + co0 + row) * KDIM + c;          // row = cout
        int prow = row >> 6, pcol = row & 63;                       // row = pixel
        gB[q] = ((size_t)(n * HP + h0 + prow) * HP + pcol) * CIN + c;
    }
    short* ldsA = lds;
    short* ldsB = lds + 4096;

    floatx4 acc[4][4];
    #pragma unroll
    for (int i = 0; i < 4; ++i)
        #pragma unroll
        for (int j = 0; j < 4; ++j) acc[i][j] = (floatx4){0.f, 0.f, 0.f, 0.f};

    const int l = t & 63;
    const int wv = t >> 6;
    const int wm = (wv & 1) * 64;   // wave's cout offset in tile
    const int wn = (wv >> 1) * 64;  // wave's pixel offset in tile
    const int lrow = l & 15;
    const int lk = (l >> 4) * 8;

    for (int kh = 0; kh < 3; ++kh)
    for (int kw = 0; kw < 3; ++kw) {
        const size_t aOff = (size_t)(kh * 3 + kw) * CIN;
        const size_t bOff = (size_t)(kh * HP + kw) * CIN;
        for (int cs = 0; cs < CIN; cs += 32) {
            __syncthreads();
            #pragma unroll
            for (int q = 0; q < 2; ++q) {
                async16(Wt + gA[q] + aOff + cs, ldsA + q * 2048 + e0);
                async16(xt + gB[q] + bOff + cs, ldsB + q * 2048 + e0);
            }
            __syncthreads();
            bf16x8 a[4], b[4];
            #pragma unroll
            for (int mi = 0; mi < 4; ++mi)
                a[mi] = *(const bf16x8*)&ldsA[(wm + mi * 16 + lrow) * 32 + lk];
            #pragma unroll
            for (int ni = 0; ni < 4; ++ni)
                b[ni] = *(const bf16x8*)&ldsB[(wn + ni * 16 + lrow) * 32 + lk];
            #pragma unroll
            for (int mi = 0; mi < 4; ++mi)
                #pragma unroll
                for (int ni = 0; ni < 4; ++ni)
                    acc[mi][ni] = __builtin_amdgcn_mfma_f32_16x16x32_bf16(
                        a[mi], b[ni], acc[mi][ni], 0, 0, 0);
        }
    }

    // epilogue: + noise_weight*noise, LeakyReLU(0.2). C/D: col=lane&15, row=quad*4+r
    const float nwv = nw_p[0];
    float nz[4];
    #pragma unroll
    for (int ni = 0; ni < 4; ++ni)
        nz[ni] = nwv * noise[(size_t)n * PIX + pos0 + wn + ni * 16 + (l & 15)];
    #pragma unroll
    for (int mi = 0; mi < 4; ++mi) {
        #pragma unroll
        for (int r = 0; r < 4; ++r) {
            int cout = co0 + wm + mi * 16 + (l >> 4) * 4 + r;
            float* orow = out + ((size_t)n * COUT + cout) * PIX + pos0 + wn;
            #pragma unroll
            for (int ni = 0; ni < 4; ++ni) {
                float v = acc[mi][ni][r] + nz[ni];
                v = v >= 0.f ? v : 0.2f * v;
                orow[ni * 16 + (l & 15)] = v;
            }
        }
    }
}

extern "C" void kernel_launch(void* const* d_in, const int* in_sizes, int n_in,
                              void* d_out, int out_size, void* d_ws, size_t ws_size,
                              hipStream_t stream) {
    const float* x       = (const float*)d_in[0];
    const float* style   = (const float*)d_in[1];
    const float* noise   = (const float*)d_in[2];
    const float* weight  = (const float*)d_in[3];
    const float* style_w = (const float*)d_in[4];
    const float* style_b = (const float*)d_in[5];
    const float* noise_w = (const float*)d_in[6];
    float* out = (float*)d_out;

    char* ws = (char*)d_ws;
    ushort* Wt = (ushort*)ws;                                   // 16*512*9*512*2 = 75,497,472 B
    ushort* xt = (ushort*)(ws + 75497472);                      // 16*66*66*512*2 = 71,368,704 B
    float*  s  = (float*)(ws + 75497472 + 71368704);            // 32 KB

    hipLaunchKernelGGL(style_kernel,  dim3(32),        dim3(256), 0, stream,
                       style, style_w, style_b, s);
    hipLaunchKernelGGL(modw_kernel,   dim3(512, 16),   dim3(256), 0, stream,
                       weight, s, Wt);
    hipLaunchKernelGGL(zborder_kernel, dim3(2080),     dim3(256), 0, stream,
                       (unsigned long long*)xt);
    hipLaunchKernelGGL(xpose_kernel,  dim3(64, 16),    dim3(256), 0, stream,
                       x, xt);
    hipLaunchKernelGGL(conv_kernel,   dim3(32, 4, 16), dim3(256), 0, stream,
                       Wt, xt, noise, noise_w, out);
}

// Round 2
// 689.917 us; speedup vs baseline: 1.0427x; 1.0427x over previous
//
#include <hip/hip_runtime.h>
#include <hip/hip_bf16.h>
#include <stdint.h>

#define NB   16
#define CIN  512
#define COUT 512
#define STY  512
#define HH   64
#define WW   64
#define KT   9          // 3x3 taps
#define KDIM (CIN*KT)   // 4608
#define HP   66         // padded spatial
#define PIX  (HH*WW)    // 4096
#define EPSV 1e-8f

typedef __attribute__((ext_vector_type(8))) __bf16 bf16x8;
typedef __attribute__((ext_vector_type(4))) float floatx4;
typedef unsigned short ushort;

__device__ __forceinline__ ushort f32_to_bf16(float f) {
    union { float f; uint32_t u; } v; v.f = f;
    uint32_t u = v.u;
    u += 0x7fffu + ((u >> 16) & 1u);   // RNE
    return (ushort)(u >> 16);
}

__device__ __forceinline__ void async16(const void* g, void* l) {
    __builtin_amdgcn_global_load_lds(
        (const __attribute__((address_space(1))) uint32_t*)g,
        (__attribute__((address_space(3))) uint32_t*)l, 16, 0, 0);
}

// ---------------- kernel 1: style linear: s[n][ci] ----------------
// grid (16, 8): block handles 64 ci outputs, 4 lanes per output.
__global__ void __launch_bounds__(256) style_kernel(
    const float* __restrict__ style, const float* __restrict__ style_w,
    const float* __restrict__ style_b, float* __restrict__ s) {
    const int n = blockIdx.x;
    const int ci = blockIdx.y * 64 + (threadIdx.x >> 2);
    const int q = threadIdx.x & 3;
    const float4* wv = (const float4*)(style_w + (size_t)ci * STY);
    const float4* sv = (const float4*)(style + (size_t)n * STY);
    float acc = 0.f;
    #pragma unroll 8
    for (int j = q; j < STY / 4; j += 4) {
        float4 a = wv[j], b = sv[j];
        acc += a.x * b.x + a.y * b.y + a.z * b.z + a.w * b.w;
    }
    acc += __shfl_down(acc, 2, 4);
    acc += __shfl_down(acc, 1, 4);
    if (q == 0) s[(size_t)n * CIN + ci] = acc + style_b[ci];
}

// ------- kernel 2: modulate + demod + transpose to Wt[n][co][kk][ci] bf16 -------
// LDS-staged: coalesced float2 global reads, all gathers hit LDS, packed uint writes.
__global__ void __launch_bounds__(256) modw_kernel(
    const float* __restrict__ weight, const float* __restrict__ s,
    ushort* __restrict__ Wt) {
    __shared__ float wL[KDIM];   // 18432 B
    __shared__ float sL[CIN];    // 2048 B
    __shared__ float red[4];
    const int co = blockIdx.x, n = blockIdx.y, t = threadIdx.x;
    const float2* wv = (const float2*)(weight + (size_t)co * KDIM);
    float2* wLv = (float2*)wL;
    #pragma unroll
    for (int i = 0; i < 9; ++i) wLv[t + 256 * i] = wv[t + 256 * i];
    ((float2*)sL)[t] = ((const float2*)(s + (size_t)n * CIN))[t];
    __syncthreads();
    // thread t owns ci = 2t, 2t+1 (9 taps each); modulated values kept in regs
    float m[18];
    float sum = 0.f;
    #pragma unroll
    for (int c = 0; c < 2; ++c) {
        int ci = 2 * t + c;
        float sm = sL[ci];
        #pragma unroll
        for (int kk = 0; kk < 9; ++kk) {
            float v = wL[ci * 9 + kk] * sm;
            m[c * 9 + kk] = v;
            sum += v * v;
        }
    }
    for (int off = 32; off > 0; off >>= 1) sum += __shfl_down(sum, off, 64);
    if ((t & 63) == 0) red[t >> 6] = sum;
    __syncthreads();
    const float demod = rsqrtf(red[0] + red[1] + red[2] + red[3] + EPSV);
    uint32_t* orow = (uint32_t*)(Wt + (size_t)(n * COUT + co) * KDIM);
    #pragma unroll
    for (int kk = 0; kk < 9; ++kk) {   // o = kk*512 + {2t,2t+1} -> uint idx kk*256+t
        uint32_t lo = (uint32_t)f32_to_bf16(m[kk] * demod);
        uint32_t hi = (uint32_t)f32_to_bf16(m[9 + kk] * demod);
        orow[kk * 256 + t] = lo | (hi << 16);
    }
}

// ------- kernel 3a: zero the padding borders of xt[n][66][66][512] (bf16) -------
__global__ void __launch_bounds__(256) zborder_kernel(unsigned long long* __restrict__ xt8) {
    int idx = blockIdx.x * 256 + threadIdx.x;  // 16*260*128 exactly
    int k = idx & 127;
    int rem = idx >> 7;
    int slot = rem % 260;
    int n = rem / 260;
    int hp, wp;
    if (slot < 66)       { hp = 0;  wp = slot; }
    else if (slot < 132) { hp = 65; wp = slot - 66; }
    else { int r = slot - 132; hp = 1 + (r >> 1); wp = (r & 1) ? 65 : 0; }
    xt8[(size_t)((n * HP + hp) * HP + wp) * 128 + k] = 0ull;
}

// ------- kernel 3b: NCHW fp32 -> padded NHWC bf16 transpose -------
// 64-ci chunks, float4 loads, packed uint (2xbf16) coalesced writes.
__global__ void __launch_bounds__(256) xpose_kernel(
    const float* __restrict__ x, ushort* __restrict__ xt) {
    const int h = blockIdx.x;   // 0..63
    const int n = blockIdx.y;
    const int t = threadIdx.x;
    __shared__ float tile[64][68];   // pad 68: rows 16B-aligned, phase2 2-way-free
    for (int ci0 = 0; ci0 < CIN; ci0 += 64) {
        #pragma unroll
        for (int r = 0; r < 4; ++r) {      // float4 loads: 16 lanes cover one ci row
            int cil = r * 16 + (t >> 4);
            int w4 = (t & 15) * 4;
            float4 v = *(const float4*)&x[(((size_t)n * CIN + ci0 + cil) * HH + h) * WW + w4];
            *(float4*)&tile[cil][w4] = v;
        }
        __syncthreads();
        #pragma unroll
        for (int r = 0; r < 8; ++r) {      // packed write: 2 ci per lane
            int w = (t >> 5) + r * 8;
            int cil = 2 * (t & 31);
            uint32_t lo = (uint32_t)f32_to_bf16(tile[cil][w]);
            uint32_t hi = (uint32_t)f32_to_bf16(tile[cil + 1][w]);
            *(uint32_t*)&xt[(((size_t)n * HP + h + 1) * HP + (w + 1)) * CIN + ci0 + cil] =
                lo | (hi << 16);
        }
        __syncthreads();
    }
}

// ------- kernel 4: implicit-GEMM conv, m97 structure (128x128 tile, BK=32) -------
// 1-D grid with XCD-aware remap: 32 pixel-tiles sharing an A-tile stay on one XCD.
__global__ void __launch_bounds__(256) conv_kernel(
    const ushort* __restrict__ Wt, const ushort* __restrict__ xt,
    const float* __restrict__ noise, const float* __restrict__ nw_p,
    float* __restrict__ out) {
    __shared__ short lds[8192];          // A: [0,4096) B: [4096,8192)  (bf16 elems)
    const int t = threadIdx.x;
    const int bid = blockIdx.x;          // 0..2047
    const int xcd = bid & 7;
    const int slot = bid >> 3;           // 0..255
    const int p = slot & 31;             // pixel tile, fastest within an XCD
    const int pair = (slot >> 5) * 8 + xcd;  // 0..63 = (co_t, n)
    const int co0 = (pair & 3) * 128;
    const int n = pair >> 2;
    const int pos0 = p * 128;
    const int h0 = p * 2;

    // staging bases: per call q, element e = q*2048 + t*8 of the 32x128 tile
    const int e0 = t * 8;
    size_t gA[2], gB[2];
    #pragma unroll
    for (int q = 0; q < 2; ++q) {
        int e = q * 2048 + e0;
        int row = e >> 5, c = e & 31;
        gA[q] = (size_t)(n * COUT + co0 + row) * KDIM + c;          // row = cout
        int prow = row >> 6, pcol = row & 63;                       // row = pixel
        gB[q] = ((size_t)(n * HP + h0 + prow) * HP + pcol) * CIN + c;
    }
    short* ldsA = lds;
    short* ldsB = lds + 4096;

    floatx4 acc[4][4];
    #pragma unroll
    for (int i = 0; i < 4; ++i)
        #pragma unroll
        for (int j = 0; j < 4; ++j) acc[i][j] = (floatx4){0.f, 0.f, 0.f, 0.f};

    const int l = t & 63;
    const int wv = t >> 6;
    const int wm = (wv & 1) * 64;   // wave's cout offset in tile
    const int wn = (wv >> 1) * 64;  // wave's pixel offset in tile
    const int lrow = l & 15;
    const int lk = (l >> 4) * 8;

    for (int kh = 0; kh < 3; ++kh)
    for (int kw = 0; kw < 3; ++kw) {
        const size_t aOff = (size_t)(kh * 3 + kw) * CIN;
        const size_t bOff = (size_t)(kh * HP + kw) * CIN;
        for (int cs = 0; cs < CIN; cs += 32) {
            __syncthreads();
            #pragma unroll
            for (int q = 0; q < 2; ++q) {
                async16(Wt + gA[q] + aOff + cs, ldsA + q * 2048 + e0);
                async16(xt + gB[q] + bOff + cs, ldsB + q * 2048 + e0);
            }
            __syncthreads();
            bf16x8 a[4], b[4];
            #pragma unroll
            for (int mi = 0; mi < 4; ++mi)
                a[mi] = *(const bf16x8*)&ldsA[(wm + mi * 16 + lrow) * 32 + lk];
            #pragma unroll
            for (int ni = 0; ni < 4; ++ni)
                b[ni] = *(const bf16x8*)&ldsB[(wn + ni * 16 + lrow) * 32 + lk];
            #pragma unroll
            for (int mi = 0; mi < 4; ++mi)
                #pragma unroll
                for (int ni = 0; ni < 4; ++ni)
                    acc[mi][ni] = __builtin_amdgcn_mfma_f32_16x16x32_bf16(
                        a[mi], b[ni], acc[mi][ni], 0, 0, 0);
        }
    }

    // epilogue: + noise_weight*noise, LeakyReLU(0.2). C/D: col=lane&15, row=quad*4+r
    const float nwv = nw_p[0];
    float nz[4];
    #pragma unroll
    for (int ni = 0; ni < 4; ++ni)
        nz[ni] = nwv * noise[(size_t)n * PIX + pos0 + wn + ni * 16 + (l & 15)];
    #pragma unroll
    for (int mi = 0; mi < 4; ++mi) {
        #pragma unroll
        for (int r = 0; r < 4; ++r) {
            int cout = co0 + wm + mi * 16 + (l >> 4) * 4 + r;
            float* orow = out + ((size_t)n * COUT + cout) * PIX + pos0 + wn;
            #pragma unroll
            for (int ni = 0; ni < 4; ++ni) {
                float v = acc[mi][ni][r] + nz[ni];
                v = v >= 0.f ? v : 0.2f * v;
                orow[ni * 16 + (l & 15)] = v;
            }
        }
    }
}

extern "C" void kernel_launch(void* const* d_in, const int* in_sizes, int n_in,
                              void* d_out, int out_size, void* d_ws, size_t ws_size,
                              hipStream_t stream) {
    const float* x       = (const float*)d_in[0];
    const float* style   = (const float*)d_in[1];
    const float* noise   = (const float*)d_in[2];
    const float* weight  = (const float*)d_in[3];
    const float* style_w = (const float*)d_in[4];
    const float* style_b = (const float*)d_in[5];
    const float* noise_w = (const float*)d_in[6];
    float* out = (float*)d_out;

    char* ws = (char*)d_ws;
    ushort* Wt = (ushort*)ws;                                   // 16*512*9*512*2 = 75,497,472 B
    ushort* xt = (ushort*)(ws + 75497472);                      // 16*66*66*512*2 = 71,368,704 B
    float*  s  = (float*)(ws + 75497472 + 71368704);            // 32 KB

    hipLaunchKernelGGL(style_kernel,   dim3(16, 8),    dim3(256), 0, stream,
                       style, style_w, style_b, s);
    hipLaunchKernelGGL(modw_kernel,    dim3(512, 16),  dim3(256), 0, stream,
                       weight, s, Wt);
    hipLaunchKernelGGL(zborder_kernel, dim3(2080),     dim3(256), 0, stream,
                       (unsigned long long*)xt);
    hipLaunchKernelGGL(xpose_kernel,   dim3(64, 16),   dim3(256), 0, stream,
                       x, xt);
    hipLaunchKernelGGL(conv_kernel,    dim3(2048),     dim3(256), 0, stream,
                       Wt, xt, noise, noise_w, out);
}